// Round 14
// baseline (22117.632 us; speedup 1.0000x reference)
//
#include <hip/hip_runtime.h>
#include <math.h>

#define BB 128   // batch
#define TT 256   // time
#define DD 256   // input dims
#define UU 512   // units
#define RR 512   // ladder order

// ws layout (floats), row-major activations (r8-proven):
//   X0 [128][512] @ 0        x_j lives in X[j&1]
//   X1 [128][512] @ 65536
//   M  [128][256] @ 131072   m_t while combo(t) runs; m_{t+1} after m_kernel
//   HZ [128][512] @ 163840   zeros (h_{-1})
#define OFF_X0 0
#define OFF_X1 65536
#define OFF_M  131072
#define OFF_HZ 163840
#define WS_FLT 229376
#define WS_NEED_BYTES (WS_FLT * 4)

__global__ __launch_bounds__(256) void zero_kernel(float* __restrict__ p, int n)
{
    int i = blockIdx.x * 256 + threadIdx.x;
    if (i < n) p[i] = 0.0f;
}

// combo(t): 256 blocks x 256 threads; tile = 4 rows x 128 cols; thread = 1 row x 2 cols.
//   bid <  128 (h-part, t>=0):  h_t = tanhf(((aH+aX)+aF)+by)
//   bid >= 128 (x-part, t<=254): x_{t+1} = aA + aB
// rg = b>>2 (32 row-groups of 4), cg = b&3 (4 col-slices of 128).
// Row index goes through readfirstlane -> SGPR -> activation broadcast loads
// become provably wave-uniform (s_load, SMEM pipe); weights are float2 VMEM.
// Bitwise contract (= np ref, proven r7/r8): each dot = ascending-k
// single-accumulator fmaf chain from 0.0f; u = inp+m (one add); f = wfm*m
// (one mul); x = aA+aB (one add); z = ((aH+aX)+aF)+by. Vector weight loads /
// scalar activation loads change addressing only, never any chain's op order.
__global__ __launch_bounds__(256) void combo_kernel(
    const float* __restrict__ inputs, const float* __restrict__ wfm,
    const float* __restrict__ by,     const float* __restrict__ WyhT,
    const float* __restrict__ WyxT,   const float* __restrict__ WyfT,
    const float* __restrict__ AT,     const float* __restrict__ BT,
    const float* __restrict__ xin,    // x_t
    const float* __restrict__ m,      // m_t
    const float* __restrict__ hz,     // zeros (h_{-1})
    float* __restrict__ xout,         // x_{t+1}
    float* __restrict__ out, int t)
{
    const int tid  = threadIdx.x;
    const int bid  = blockIdx.x;
    const int lane = tid & 63;
    const int wvu  = __builtin_amdgcn_readfirstlane(tid >> 6);  // wave id, SGPR
    const bool is_h = bid < 128;
    const int b    = bid & 127;
    const int cg   = b & 3;
    const int rg   = b >> 2;
    const int row  = rg * 4 + wvu;        // SGPR-resident row index
    const int c    = cg * 128 + lane * 2;

    if (is_h) {
        if (t < 0) return;
        const float* hr = (t == 0) ? (hz + row * UU)
                                   : (out + (row * TT + (t - 1)) * UU);
        const float* xr = xin + row * RR;
        float ah0 = 0.0f, ah1 = 0.0f, ax0 = 0.0f, ax1 = 0.0f;
        #pragma unroll 16
        for (int k = 0; k < UU; ++k) {
            float2 wh = *reinterpret_cast<const float2*>(&WyhT[k * UU + c]);
            float2 wx = *reinterpret_cast<const float2*>(&WyxT[k * UU + c]);
            float hv = hr[k];                  // wave-uniform -> s_load
            float xv = xr[k];
            ah0 = fmaf(hv, wh.x, ah0);
            ah1 = fmaf(hv, wh.y, ah1);
            ax0 = fmaf(xv, wx.x, ax0);
            ax1 = fmaf(xv, wx.y, ax1);
        }
        const float* mr = m + row * DD;
        float af0 = 0.0f, af1 = 0.0f;
        #pragma unroll 16
        for (int d = 0; d < DD; ++d) {
            float2 wf = *reinterpret_cast<const float2*>(&WyfT[d * UU + c]);
            float f = wfm[d] * mr[d];          // f = wfm*m_t (one mul, shared bits)
            af0 = fmaf(f, wf.x, af0);
            af1 = fmaf(f, wf.y, af1);
        }
        float2 byv = *reinterpret_cast<const float2*>(&by[c]);
        float2 r;
        r.x = tanhf(((ah0 + ax0) + af0) + byv.x);
        r.y = tanhf(((ah1 + ax1) + af1) + byv.y);
        *reinterpret_cast<float2*>(&out[(row * TT + t) * UU + c]) = r;
    } else {
        if (t >= TT - 1) return;
        const float* xr = xin + row * RR;
        float a0 = 0.0f, a1 = 0.0f;
        #pragma unroll 16
        for (int k = 0; k < RR; ++k) {
            float2 wA = *reinterpret_cast<const float2*>(&AT[k * RR + c]);
            float xv = xr[k];                  // wave-uniform -> s_load
            a0 = fmaf(xv, wA.x, a0);
            a1 = fmaf(xv, wA.y, a1);
        }
        const float* ir = inputs + (row * TT + (t + 1)) * DD;
        const float* mr = m + row * DD;
        float b0 = 0.0f, b1 = 0.0f;
        #pragma unroll 16
        for (int d = 0; d < DD; ++d) {
            float2 wB = *reinterpret_cast<const float2*>(&BT[d * RR + c]);
            float u = ir[d] + mr[d];           // u = inp_{t+1}+m_t (one add, shared bits)
            b0 = fmaf(u, wB.x, b0);
            b1 = fmaf(u, wB.y, b1);
        }
        float2 r;
        r.x = a0 + b0;                         // dot + dot, one add each
        r.y = a1 + b1;
        *reinterpret_cast<float2*>(&xout[row * RR + c]) = r;
    }
}

// m_{t+1} = x_{t+1} @ CT: 64 blocks; tile 4 rows x 128 cols; thread = 1 row x 2 cols.
__global__ __launch_bounds__(256) void m_kernel(
    const float* __restrict__ CT, const float* __restrict__ x,
    float* __restrict__ m)
{
    const int tid  = threadIdx.x;
    const int bid  = blockIdx.x;
    const int lane = tid & 63;
    const int wvu  = __builtin_amdgcn_readfirstlane(tid >> 6);
    const int cg   = bid & 1;
    const int rg   = bid >> 1;
    const int row  = rg * 4 + wvu;
    const int c    = cg * 128 + lane * 2;

    const float* xr = x + row * RR;
    float a0 = 0.0f, a1 = 0.0f;
    #pragma unroll 16
    for (int k = 0; k < RR; ++k) {
        float2 wC = *reinterpret_cast<const float2*>(&CT[k * DD + c]);
        float xv = xr[k];                      // wave-uniform -> s_load
        a0 = fmaf(xv, wC.x, a0);
        a1 = fmaf(xv, wC.y, a1);
    }
    float2 r;
    r.x = a0;
    r.y = a1;
    *reinterpret_cast<float2*>(&m[row * DD + c]) = r;
}

__global__ __launch_bounds__(64) void sentinel_kernel(float* __restrict__ out, float v)
{
    if (threadIdx.x == 0 && blockIdx.x == 0) out[0] = v;
}

extern "C" void kernel_launch(void* const* d_in, const int* in_sizes, int n_in,
                              void* d_out, int out_size, void* d_ws, size_t ws_size,
                              hipStream_t stream)
{
    const float* inputs = (const float*)d_in[0];
    const float* wfm    = (const float*)d_in[1];
    const float* WyhT   = (const float*)d_in[2];
    const float* WyxT   = (const float*)d_in[3];
    const float* WyfT   = (const float*)d_in[4];
    const float* by     = (const float*)d_in[5];
    const float* AT     = (const float*)d_in[6];
    const float* BT     = (const float*)d_in[7];
    const float* CT     = (const float*)d_in[8];
    float* out = (float*)d_out;
    float* ws  = (float*)d_ws;

    // Environment sentinels (absmax reveals code if triggered).
    double code = 0.0;
    static const int exp_sizes[9] = {8388608, 256, 262144, 262144, 131072,
                                     512, 262144, 131072, 131072};
    if (n_in != 9) {
        code = 3.0e6 + n_in;
    } else {
        for (int i = 0; i < 9; ++i)
            if (in_sizes[i] != exp_sizes[i]) { code = 2.0e6 + i * 1.0e4; break; }
    }
    if (code == 0.0 && out_size != BB * TT * UU)
        code = 4.0e6 + (double)(out_size / 10000);
    if (code == 0.0 && ws_size < (size_t)WS_NEED_BYTES)
        code = 1.0e6 + (double)(ws_size / 1024);
    if (code != 0.0) {
        sentinel_kernel<<<1, 64, 0, stream>>>(out, (float)code);
        return;
    }

    float* X0 = ws + OFF_X0;
    float* X1 = ws + OFF_X1;
    float* M  = ws + OFF_M;
    float* HZ = ws + OFF_HZ;

    // Zero X1 (x_{-1}), M (m_{-1}), HZ (h_{-1}); X0 written before read.
    zero_kernel<<<(WS_FLT + 255) / 256, 256, 0, stream>>>(ws, WS_FLT);

    // t=-1: x-part -> x_0 (h-part self-disables); then m_0 = x_0@CT.
    combo_kernel<<<256, 256, 0, stream>>>(inputs, wfm, by, WyhT, WyxT, WyfT, AT, BT,
                                          X1, M, HZ, X0, out, -1);
    m_kernel<<<64, 256, 0, stream>>>(CT, X0, M);

    // t = 0..254: combo(t) = { h_t ; x_{t+1} }, then m_{t+1} = x_{t+1}@CT.
    for (int t = 0; t < TT - 1; ++t) {
        float* xc = (t & 1) ? X1 : X0;   // x_t
        float* xn = (t & 1) ? X0 : X1;   // x_{t+1}
        combo_kernel<<<256, 256, 0, stream>>>(inputs, wfm, by, WyhT, WyxT, WyfT, AT, BT,
                                              xc, M, HZ, xn, out, t);
        m_kernel<<<64, 256, 0, stream>>>(CT, xn, M);
    }
    // t = 255: h_255 only (x-part self-disables). x_255 lives in X1 (255 odd).
    combo_kernel<<<256, 256, 0, stream>>>(inputs, wfm, by, WyhT, WyxT, WyfT, AT, BT,
                                          X1, M, HZ, X0, out, TT - 1);
}